// Round 5
// baseline (644.083 us; speedup 1.0000x reference)
//
#include <hip/hip_runtime.h>

#define BB 64
#define WW 4096
#define HH 128
#define NCHUNK 32
#define CROWS 128          // rows per chunk = WW / NCHUNK
#define PSTRIDE 132        // per-(b,chunk) partial: acc[128], m, l (+2 pad)

__device__ inline float sigmoidf(float x) { return 1.0f / (1.0f + expf(-x)); }

// ---------------------------------------------------------------------------
// Single fused kernel: per-chunk attention partials + per-batch tail, linked
// by a device-scope completion counter (last-chunk-done runs the tail for its
// batch; no second launch, no full-grid drain).
__global__ __launch_bounds__(256, 4)
void fused_all(const float* __restrict__ enc,
               const float* __restrict__ h0,
               const float* __restrict__ c0,
               const float* __restrict__ attW,
               const float* __restrict__ attb,
               const float* __restrict__ input,
               const float* __restrict__ inpW,
               const float* __restrict__ inpb,
               const float* __restrict__ Wih0,
               const float* __restrict__ Whh0,
               const float* __restrict__ bih0,
               const float* __restrict__ bhh0,
               const float* __restrict__ Wih1,
               const float* __restrict__ Whh1,
               const float* __restrict__ bih1,
               const float* __restrict__ bhh1,
               float* __restrict__ partials,
               int* __restrict__ counters,
               float* __restrict__ out) {
    __shared__ float s_wa[128];
    __shared__ float s_red[128];
    __shared__ float s_sc[CROWS];    // raw scores of tile rows
    __shared__ float s_p[CROWS];     // shifted exp-weights
    __shared__ float racc[16 * 128];
    __shared__ float s_bias, s_m, s_extra;
    __shared__ int s_win;

    const int t = threadIdx.x;
    const int b = blockIdx.x >> 5;
    const int chunk = blockIdx.x & 31;
    const int w0 = chunk * CROWS;

    // --- bias_b = sum_h h0[-1]*c0[-1]*wa_st + att_b ; cache wa_enc
    if (t < 128) {
        s_wa[t] = attW[t];
        float hv = h0[BB * HH + b * HH + t];
        float cv = c0[BB * HH + b * HH + t];
        s_red[t] = hv * cv * attW[HH + t];
    }
    __syncthreads();
    for (int s = 64; s > 0; s >>= 1) {
        if (t < s) s_red[t] += s_red[t + s];
        __syncthreads();
    }
    if (t == 0) s_bias = s_red[0] + attb[0];
    __syncthreads();
    const float bias = s_bias;

    const int seg = t & 15;   // h-segment (8 floats)
    const int rg  = t >> 4;   // row group 0..15
    float wseg[8];
#pragma unroll
    for (int j = 0; j < 8; j++) wseg[j] = s_wa[seg * 8 + j];

    // --- load tile into registers + compute scores
    float4 ra[8], rc[8];
#pragma unroll
    for (int pass = 0; pass < 8; pass++) {
        const int r = pass * 16 + rg;
        const float4* p = (const float4*)(enc + ((size_t)b * WW + w0 + r) * HH + seg * 8);
        ra[pass] = p[0];
        rc[pass] = p[1];
        float d = ra[pass].x * wseg[0] + ra[pass].y * wseg[1]
                + ra[pass].z * wseg[2] + ra[pass].w * wseg[3]
                + rc[pass].x * wseg[4] + rc[pass].y * wseg[5]
                + rc[pass].z * wseg[6] + rc[pass].w * wseg[7];
        d += __shfl_xor(d, 8, 16);
        d += __shfl_xor(d, 4, 16);
        d += __shfl_xor(d, 2, 16);
        d += __shfl_xor(d, 1, 16);
        if (seg == 0) s_sc[r] = d + bias;
    }

    // --- extra score: row w0-1 (only chunk>0)
    if (chunk > 0 && t < 16) {
        const float4* p = (const float4*)(enc + ((size_t)b * WW + w0 - 1) * HH + t * 8);
        float4 a = p[0], c = p[1];
        float d = a.x * wseg[0] + a.y * wseg[1] + a.z * wseg[2] + a.w * wseg[3]
                + c.x * wseg[4] + c.y * wseg[5] + c.z * wseg[6] + c.w * wseg[7];
        d += __shfl_xor(d, 8, 16);
        d += __shfl_xor(d, 4, 16);
        d += __shfl_xor(d, 2, 16);
        d += __shfl_xor(d, 1, 16);
        if (t == 0) s_extra = d + bias;
    }
    __syncthreads();

    // --- shifted scores: s_p[r] = score(w0+r-1); chunk0 r0 -> zero col (tail)
    if (t < 128) {
        float v;
        if (t == 0) v = (chunk > 0) ? s_extra : -1e30f;
        else        v = s_sc[t - 1];
        s_p[t] = v;
    }
    __syncthreads();

    // --- chunk max m over s_p
    if (t < 64) s_red[t] = fmaxf(s_p[t], s_p[t + 64]);
    __syncthreads();
    for (int s = 32; s > 0; s >>= 1) {
        if (t < s) s_red[t] = fmaxf(s_red[t], s_red[t + s]);
        __syncthreads();
    }
    if (t == 0) s_m = s_red[0];
    __syncthreads();
    const float m = s_m;

    // --- p = exp(s_ext - m); l = sum
    if (t < 128) s_p[t] = expf(s_p[t] - m);
    __syncthreads();
    if (t < 64) s_red[t] = s_p[t] + s_p[t + 64];
    __syncthreads();
    for (int s = 32; s > 0; s >>= 1) {
        if (t < s) s_red[t] += s_red[t + s];
        __syncthreads();
    }

    // --- weighted accumulation straight from registers
    float acc8[8];
#pragma unroll
    for (int j = 0; j < 8; j++) acc8[j] = 0.f;
#pragma unroll
    for (int pass = 0; pass < 8; pass++) {
        const int r = pass * 16 + rg;
        const float pw = s_p[r];
        acc8[0] += pw * ra[pass].x; acc8[1] += pw * ra[pass].y;
        acc8[2] += pw * ra[pass].z; acc8[3] += pw * ra[pass].w;
        acc8[4] += pw * rc[pass].x; acc8[5] += pw * rc[pass].y;
        acc8[6] += pw * rc[pass].z; acc8[7] += pw * rc[pass].w;
    }
#pragma unroll
    for (int j = 0; j < 8; j++) racc[rg * 128 + seg * 8 + j] = acc8[j];
    __syncthreads();

    float* pout = partials + (size_t)(b * NCHUNK + chunk) * PSTRIDE;
    if (t < 128) {
        float s = 0.f;
#pragma unroll
        for (int w2 = 0; w2 < 16; w2++) s += racc[w2 * 128 + t];
        pout[t] = s;
    }
    if (t == 128) pout[128] = m;
    if (t == 129) pout[129] = s_red[0];

    // --- release: make this block's partial visible at device scope, then
    //     bump the batch counter. Last chunk (old==31) runs the tail.
    __threadfence();
    __syncthreads();
    if (t == 0) {
        int old = atomicAdd(&counters[b], 1);
        s_win = (old == NCHUNK - 1) ? 1 : 0;
    }
    __syncthreads();
    if (!s_win) return;
    __threadfence();   // acquire: invalidate stale cached partials

    // ======================= per-batch tail (winner block) ==================
    __shared__ float lm[NCHUNK], llv[NCHUNK], ls[NCHUNK];
    __shared__ float sM, sL;
    __shared__ float xc[256];       // [x | input]
    __shared__ float sxv[128];      // xin
    __shared__ float shv[128];      // h_prev L0
    __shared__ float sh1[128];      // h1
    __shared__ float shv2[128];     // h_prev L1
    __shared__ float gates[512];

    if (t < NCHUNK) {
        const float* pp = partials + (size_t)(b * NCHUNK + t) * PSTRIDE;
        lm[t] = pp[128];
        llv[t] = pp[129];
    }
    __syncthreads();
    if (t == 0) {
        float M = 0.0f;   // include the zero column
        for (int c = 0; c < NCHUNK; c++) M = fmaxf(M, lm[c]);
        float L = expf(-M);
        for (int c = 0; c < NCHUNK; c++) {
            float s = expf(lm[c] - M);
            ls[c] = s;
            L += s * llv[c];
        }
        sM = M; sL = L;
    }
    __syncthreads();

    // x[h] = (exp(-M)*enc[b,0,h] + sum_c ls[c]*acc_c[h]) / L
    if (t < 128) {
        float xv = expf(-sM) * enc[(size_t)b * WW * HH + t];
        for (int c = 0; c < NCHUNK; c++)
            xv += ls[c] * partials[(size_t)(b * NCHUNK + c) * PSTRIDE + t];
        xc[t] = xv / sL;
        xc[128 + t] = input[b * HH + t];
    }
    __syncthreads();

    // xin = inp_W . concat(x, input) + inp_b
    if (t < 128) {
        float a = inpb[t];
        const float4* wr = (const float4*)(inpW + (size_t)t * 256);
#pragma unroll
        for (int k = 0; k < 64; k++) {
            float4 w4 = wr[k];
            a += xc[4 * k] * w4.x + xc[4 * k + 1] * w4.y
               + xc[4 * k + 2] * w4.z + xc[4 * k + 3] * w4.w;
        }
        sxv[t] = a;
        shv[t] = h0[b * HH + t];
        shv2[t] = h0[BB * HH + b * HH + t];
    }
    __syncthreads();

    // ---- LSTM layer 0: 512 gate rows on 256 threads (2 each)
#pragma unroll
    for (int rr = 0; rr < 2; rr++) {
        const int row = t + rr * 256;
        float g = bih0[row] + bhh0[row];
        const float4* wi = (const float4*)(Wih0 + (size_t)row * 128);
        const float4* wh = (const float4*)(Whh0 + (size_t)row * 128);
#pragma unroll
        for (int k = 0; k < 32; k++) {
            float4 a = wi[k], c = wh[k];
            g += sxv[4 * k] * a.x + sxv[4 * k + 1] * a.y + sxv[4 * k + 2] * a.z + sxv[4 * k + 3] * a.w
               + shv[4 * k] * c.x + shv[4 * k + 1] * c.y + shv[4 * k + 2] * c.z + shv[4 * k + 3] * c.w;
        }
        gates[row] = g;
    }
    __syncthreads();
    if (t < 128) {
        float ig = sigmoidf(gates[t]);
        float fg = sigmoidf(gates[128 + t]);
        float gg = tanhf(gates[256 + t]);
        float og = sigmoidf(gates[384 + t]);
        float cn = fg * c0[b * HH + t] + ig * gg;
        float hn = og * tanhf(cn);
        out[8192 + b * HH + t] = hn;    // h-stack layer 0
        out[24576 + b * HH + t] = cn;   // c-stack layer 0
        sh1[t] = hn;
    }
    __syncthreads();

    // ---- LSTM layer 1
#pragma unroll
    for (int rr = 0; rr < 2; rr++) {
        const int row = t + rr * 256;
        float g = bih1[row] + bhh1[row];
        const float4* wi = (const float4*)(Wih1 + (size_t)row * 128);
        const float4* wh = (const float4*)(Whh1 + (size_t)row * 128);
#pragma unroll
        for (int k = 0; k < 32; k++) {
            float4 a = wi[k], c = wh[k];
            g += sh1[4 * k] * a.x + sh1[4 * k + 1] * a.y + sh1[4 * k + 2] * a.z + sh1[4 * k + 3] * a.w
               + shv2[4 * k] * c.x + shv2[4 * k + 1] * c.y + shv2[4 * k + 2] * c.z + shv2[4 * k + 3] * c.w;
        }
        gates[row] = g;
    }
    __syncthreads();
    if (t < 128) {
        float ig = sigmoidf(gates[t]);
        float fg = sigmoidf(gates[128 + t]);
        float gg = tanhf(gates[256 + t]);
        float og = sigmoidf(gates[384 + t]);
        float cn = fg * c0[BB * HH + b * HH + t] + ig * gg;
        float hn = og * tanhf(cn);
        out[b * HH + t] = hn;           // output = h2
        out[16384 + b * HH + t] = hn;   // h-stack layer 1
        out[32768 + b * HH + t] = cn;   // c-stack layer 1
    }
}

// ---------------------------------------------------------------------------
extern "C" void kernel_launch(void* const* d_in, const int* in_sizes, int n_in,
                              void* d_out, int out_size, void* d_ws, size_t ws_size,
                              hipStream_t stream) {
    const float* input = (const float*)d_in[0];
    const float* h0    = (const float*)d_in[1];
    const float* c0    = (const float*)d_in[2];
    const float* enc   = (const float*)d_in[3];
    const float* attW  = (const float*)d_in[4];
    const float* attb  = (const float*)d_in[5];
    const float* inpW  = (const float*)d_in[6];
    const float* inpb  = (const float*)d_in[7];
    const float* Wih0  = (const float*)d_in[8];
    const float* Whh0  = (const float*)d_in[9];
    const float* bih0  = (const float*)d_in[10];
    const float* bhh0  = (const float*)d_in[11];
    const float* Wih1  = (const float*)d_in[12];
    const float* Whh1  = (const float*)d_in[13];
    const float* bih1  = (const float*)d_in[14];
    const float* bhh1  = (const float*)d_in[15];

    float* partials = (float*)d_ws;                       // 64*32*132 floats
    int* counters   = (int*)(partials + (size_t)BB * NCHUNK * PSTRIDE);

    hipMemsetAsync(counters, 0, BB * sizeof(int), stream);
    fused_all<<<BB * NCHUNK, 256, 0, stream>>>(enc, h0, c0, attW, attb,
                                               input, inpW, inpb,
                                               Wih0, Whh0, bih0, bhh0,
                                               Wih1, Whh1, bih1, bhh1,
                                               partials, counters, (float*)d_out);
}

// Round 6
// 271.105 us; speedup vs baseline: 2.3758x; 2.3758x over previous
//
#include <hip/hip_runtime.h>

#define BB 64
#define WW 4096
#define HH 128
#define NCHUNK 32
#define CROWS 128          // rows per chunk = WW / NCHUNK
#define PSTRIDE 132        // per-(b,chunk) partial: acc[128], m, l (+2 pad)

__device__ inline float sigmoidf(float x) { return 1.0f / (1.0f + expf(-x)); }

// ---------------------------------------------------------------------------
// K1: fully fused single-pass attention chunk (R4 structure, load-first).
// Block (b, chunk) loads enc rows [w0, w0+128) into REGISTERS (64 VGPR/lane)
// FIRST (hides HBM latency behind the bias reduction), computes scores,
// builds shifted weights s_ext[r] = score(w0+r-1), chunk-local (m,l), then
// accumulates acc[h] = sum_r exp(s_ext[r]-m) * enc[w0+r, h] from registers.
// Single HBM pass over enc. No cross-block fences (R5 lesson: device-scope
// release/acquire = per-XCD L2 writeback/invalidate, catastrophic).
__global__ void fused_attention(const float* __restrict__ enc,
                                const float* __restrict__ h0,
                                const float* __restrict__ c0,
                                const float* __restrict__ attW,
                                const float* __restrict__ attb,
                                float* __restrict__ partials) {
    __shared__ float s_wa[128];
    __shared__ float s_red[128];
    __shared__ float s_sc[CROWS];    // raw scores of tile rows
    __shared__ float s_p[CROWS];     // shifted exp-weights
    __shared__ float racc[16 * 128];
    __shared__ float s_bias, s_m, s_extra;

    const int t = threadIdx.x;
    const int b = blockIdx.x >> 5;
    const int chunk = blockIdx.x & 31;
    const int w0 = chunk * CROWS;

    const int seg = t & 15;   // h-segment (8 floats)
    const int rg  = t >> 4;   // row group 0..15

    // --- issue tile loads FIRST (latency overlaps the bias reduction below)
    float4 ra[8], rc[8];
#pragma unroll
    for (int pass = 0; pass < 8; pass++) {
        const int r = pass * 16 + rg;
        const float4* p = (const float4*)(enc + ((size_t)b * WW + w0 + r) * HH + seg * 8);
        ra[pass] = p[0];
        rc[pass] = p[1];
    }

    // --- bias_b = sum_h h0[-1]*c0[-1]*wa_st + att_b ; cache wa_enc
    if (t < 128) {
        s_wa[t] = attW[t];
        float hv = h0[BB * HH + b * HH + t];
        float cv = c0[BB * HH + b * HH + t];
        s_red[t] = hv * cv * attW[HH + t];
    }
    __syncthreads();
    for (int s = 64; s > 0; s >>= 1) {
        if (t < s) s_red[t] += s_red[t + s];
        __syncthreads();
    }
    if (t == 0) s_bias = s_red[0] + attb[0];
    __syncthreads();
    const float bias = s_bias;

    float wseg[8];
#pragma unroll
    for (int j = 0; j < 8; j++) wseg[j] = s_wa[seg * 8 + j];

    // --- scores from registers
#pragma unroll
    for (int pass = 0; pass < 8; pass++) {
        const int r = pass * 16 + rg;
        float d = ra[pass].x * wseg[0] + ra[pass].y * wseg[1]
                + ra[pass].z * wseg[2] + ra[pass].w * wseg[3]
                + rc[pass].x * wseg[4] + rc[pass].y * wseg[5]
                + rc[pass].z * wseg[6] + rc[pass].w * wseg[7];
        d += __shfl_xor(d, 8, 16);
        d += __shfl_xor(d, 4, 16);
        d += __shfl_xor(d, 2, 16);
        d += __shfl_xor(d, 1, 16);
        if (seg == 0) s_sc[r] = d + bias;
    }

    // --- extra score: row w0-1 (only chunk>0); lanes 0..15
    if (chunk > 0 && t < 16) {
        const float4* p = (const float4*)(enc + ((size_t)b * WW + w0 - 1) * HH + t * 8);
        float4 a = p[0], c = p[1];
        float d = a.x * wseg[0] + a.y * wseg[1] + a.z * wseg[2] + a.w * wseg[3]
                + c.x * wseg[4] + c.y * wseg[5] + c.z * wseg[6] + c.w * wseg[7];
        d += __shfl_xor(d, 8, 16);
        d += __shfl_xor(d, 4, 16);
        d += __shfl_xor(d, 2, 16);
        d += __shfl_xor(d, 1, 16);
        if (t == 0) s_extra = d + bias;
    }
    __syncthreads();

    // --- shifted scores: s_p[r] = score(w0+r-1); chunk0 r0 -> zero col (tail)
    if (t < 128) {
        float v;
        if (t == 0) v = (chunk > 0) ? s_extra : -1e30f;
        else        v = s_sc[t - 1];
        s_p[t] = v;
    }
    __syncthreads();

    // --- chunk max m over s_p
    if (t < 64) s_red[t] = fmaxf(s_p[t], s_p[t + 64]);
    __syncthreads();
    for (int s = 32; s > 0; s >>= 1) {
        if (t < s) s_red[t] = fmaxf(s_red[t], s_red[t + s]);
        __syncthreads();
    }
    if (t == 0) s_m = s_red[0];
    __syncthreads();
    const float m = s_m;

    // --- p = exp(s_ext - m); l = sum
    if (t < 128) s_p[t] = expf(s_p[t] - m);
    __syncthreads();
    if (t < 64) s_red[t] = s_p[t] + s_p[t + 64];
    __syncthreads();
    for (int s = 32; s > 0; s >>= 1) {
        if (t < s) s_red[t] += s_red[t + s];
        __syncthreads();
    }
    // s_red[0] = l

    // --- weighted accumulation straight from registers
    float acc8[8];
#pragma unroll
    for (int j = 0; j < 8; j++) acc8[j] = 0.f;
#pragma unroll
    for (int pass = 0; pass < 8; pass++) {
        const int r = pass * 16 + rg;
        const float pw = s_p[r];       // LDS broadcast across the 16 seg-lanes
        acc8[0] += pw * ra[pass].x; acc8[1] += pw * ra[pass].y;
        acc8[2] += pw * ra[pass].z; acc8[3] += pw * ra[pass].w;
        acc8[4] += pw * rc[pass].x; acc8[5] += pw * rc[pass].y;
        acc8[6] += pw * rc[pass].z; acc8[7] += pw * rc[pass].w;
    }
#pragma unroll
    for (int j = 0; j < 8; j++) racc[rg * 128 + seg * 8 + j] = acc8[j];
    __syncthreads();

    float* out = partials + (size_t)(b * NCHUNK + chunk) * PSTRIDE;
    if (t < 128) {
        float s = 0.f;
#pragma unroll
        for (int w2 = 0; w2 < 16; w2++) s += racc[w2 * 128 + t];
        out[t] = s;
    }
    if (t == 128) out[128] = m;
    if (t == 129) out[129] = s_red[0];
}

// ---------------------------------------------------------------------------
// K2: per-batch tail. Merge 32 chunk partials -> x; xin GEMV; LSTM0; LSTM1.
// grid = BB blocks, 512 threads.
__global__ void tail_kernel(const float* __restrict__ partials,
                            const float* __restrict__ enc,
                            const float* __restrict__ input,
                            const float* __restrict__ inpW,
                            const float* __restrict__ inpb,
                            const float* __restrict__ Wih0,
                            const float* __restrict__ Whh0,
                            const float* __restrict__ bih0,
                            const float* __restrict__ bhh0,
                            const float* __restrict__ Wih1,
                            const float* __restrict__ Whh1,
                            const float* __restrict__ bih1,
                            const float* __restrict__ bhh1,
                            const float* __restrict__ h0,
                            const float* __restrict__ c0,
                            float* __restrict__ out) {
    __shared__ float lm[NCHUNK], llv[NCHUNK], ls[NCHUNK];
    __shared__ float sM, sL;
    __shared__ float xc[256];       // [x | input]
    __shared__ float sxv[128];      // xin
    __shared__ float shv[128];      // h_prev
    __shared__ float sh1[128];      // h1
    __shared__ float shv2[128];     // h_prev layer 1
    __shared__ float gates[512];

    const int b = blockIdx.x;
    const int t = threadIdx.x;

    if (t < NCHUNK) {
        const float* pp = partials + (size_t)(b * NCHUNK + t) * PSTRIDE;
        lm[t] = pp[128];
        llv[t] = pp[129];
    }
    __syncthreads();
    if (t == 0) {
        float M = 0.0f;   // include the zero column in the max
        for (int c = 0; c < NCHUNK; c++) M = fmaxf(M, lm[c]);
        float L = expf(-M);   // zero column's contribution
        for (int c = 0; c < NCHUNK; c++) {
            float s = expf(lm[c] - M);
            ls[c] = s;
            L += s * llv[c];
        }
        sM = M; sL = L;
    }
    __syncthreads();

    // x[h] = (exp(-M)*enc[b,0,h] + sum_c ls[c]*acc_c[h]) / L
    if (t < 128) {
        float xv = expf(-sM) * enc[(size_t)b * WW * HH + t];
        for (int c = 0; c < NCHUNK; c++)
            xv += ls[c] * partials[(size_t)(b * NCHUNK + c) * PSTRIDE + t];
        xc[t] = xv / sL;
        xc[128 + t] = input[b * HH + t];
    }
    __syncthreads();

    // xin = inp_W . concat(x, input) + inp_b
    if (t < 128) {
        float a = inpb[t];
        const float4* wr = (const float4*)(inpW + (size_t)t * 256);
#pragma unroll
        for (int k = 0; k < 64; k++) {
            float4 w4 = wr[k];
            a += xc[4 * k] * w4.x + xc[4 * k + 1] * w4.y
               + xc[4 * k + 2] * w4.z + xc[4 * k + 3] * w4.w;
        }
        sxv[t] = a;
        shv[t] = h0[b * HH + t];
        shv2[t] = h0[BB * HH + b * HH + t];
    }
    __syncthreads();

    // ---- LSTM layer 0: 512 gate rows
    {
        float g = bih0[t] + bhh0[t];
        const float4* wi = (const float4*)(Wih0 + (size_t)t * 128);
        const float4* wh = (const float4*)(Whh0 + (size_t)t * 128);
#pragma unroll
        for (int k = 0; k < 32; k++) {
            float4 a = wi[k], c = wh[k];
            g += sxv[4 * k] * a.x + sxv[4 * k + 1] * a.y + sxv[4 * k + 2] * a.z + sxv[4 * k + 3] * a.w
               + shv[4 * k] * c.x + shv[4 * k + 1] * c.y + shv[4 * k + 2] * c.z + shv[4 * k + 3] * c.w;
        }
        gates[t] = g;
    }
    __syncthreads();
    if (t < 128) {
        float ig = sigmoidf(gates[t]);
        float fg = sigmoidf(gates[128 + t]);
        float gg = tanhf(gates[256 + t]);
        float og = sigmoidf(gates[384 + t]);
        float cn = fg * c0[b * HH + t] + ig * gg;
        float hn = og * tanhf(cn);
        out[8192 + b * HH + t] = hn;    // h-stack layer 0
        out[24576 + b * HH + t] = cn;   // c-stack layer 0
        sh1[t] = hn;
    }
    __syncthreads();

    // ---- LSTM layer 1
    {
        float g = bih1[t] + bhh1[t];
        const float4* wi = (const float4*)(Wih1 + (size_t)t * 128);
        const float4* wh = (const float4*)(Whh1 + (size_t)t * 128);
#pragma unroll
        for (int k = 0; k < 32; k++) {
            float4 a = wi[k], c = wh[k];
            g += sh1[4 * k] * a.x + sh1[4 * k + 1] * a.y + sh1[4 * k + 2] * a.z + sh1[4 * k + 3] * a.w
               + shv2[4 * k] * c.x + shv2[4 * k + 1] * c.y + shv2[4 * k + 2] * c.z + shv2[4 * k + 3] * c.w;
        }
        gates[t] = g;
    }
    __syncthreads();
    if (t < 128) {
        float ig = sigmoidf(gates[t]);
        float fg = sigmoidf(gates[128 + t]);
        float gg = tanhf(gates[256 + t]);
        float og = sigmoidf(gates[384 + t]);
        float cn = fg * c0[BB * HH + b * HH + t] + ig * gg;
        float hn = og * tanhf(cn);
        out[b * HH + t] = hn;           // output = h2
        out[16384 + b * HH + t] = hn;   // h-stack layer 1
        out[32768 + b * HH + t] = cn;   // c-stack layer 1
    }
}

// ---------------------------------------------------------------------------
extern "C" void kernel_launch(void* const* d_in, const int* in_sizes, int n_in,
                              void* d_out, int out_size, void* d_ws, size_t ws_size,
                              hipStream_t stream) {
    const float* input = (const float*)d_in[0];
    const float* h0    = (const float*)d_in[1];
    const float* c0    = (const float*)d_in[2];
    const float* enc   = (const float*)d_in[3];
    const float* attW  = (const float*)d_in[4];
    const float* attb  = (const float*)d_in[5];
    const float* inpW  = (const float*)d_in[6];
    const float* inpb  = (const float*)d_in[7];
    const float* Wih0  = (const float*)d_in[8];
    const float* Whh0  = (const float*)d_in[9];
    const float* bih0  = (const float*)d_in[10];
    const float* bhh0  = (const float*)d_in[11];
    const float* Wih1  = (const float*)d_in[12];
    const float* Whh1  = (const float*)d_in[13];
    const float* bih1  = (const float*)d_in[14];
    const float* bhh1  = (const float*)d_in[15];

    float* partials = (float*)d_ws;   // 64*32*132 floats = 1.08 MB

    fused_attention<<<BB * NCHUNK, 256, 0, stream>>>(enc, h0, c0, attW, attb, partials);
    tail_kernel<<<BB, 512, 0, stream>>>(partials, enc, input, inpW, inpb,
                                        Wih0, Whh0, bih0, bhh0,
                                        Wih1, Whh1, bih1, bhh1,
                                        h0, c0, (float*)d_out);
}